// Round 2
// baseline (381.565 us; speedup 1.0000x reference)
//
#include <hip/hip_runtime.h>

// External I/O is fp32 (reference dtype); internal tensors bf16 for MFMA.

typedef unsigned short u16;
typedef __bf16 bf16_t;
typedef bf16_t bf16x8 __attribute__((ext_vector_type(8)));
typedef float f32x4 __attribute__((ext_vector_type(4)));

static __device__ __forceinline__ u16 f2bf(float f) {
  unsigned int u = __builtin_bit_cast(unsigned int, f);
  u += 0x7FFFu + ((u >> 16) & 1u);
  return (u16)(u >> 16);
}
static __device__ __forceinline__ bf16x8 ldfrag(const u16* p) {
  return __builtin_bit_cast(bf16x8, *(const uint4*)p);
}
// load 8 fp32, round to bf16, store as one uint4 into LDS
static __device__ __forceinline__ void stage8_f32(u16* dst, const float* src) {
  float4 a = *(const float4*)src, b = *(const float4*)(src + 4);
  u16 t[8] = {f2bf(a.x), f2bf(a.y), f2bf(a.z), f2bf(a.w),
              f2bf(b.x), f2bf(b.y), f2bf(b.z), f2bf(b.w)};
  *(uint4*)dst = *(const uint4*)t;
}

// ---------------------------------------------------------------------------
// NT GEMM: C[m,n] = sum_k A[m,k] * W[n,k] + bias[n].  M=4096, K=768 fixed.
// Tile 128x128, BK=64, 4 waves each 64x64 (4x4 of 16x16x32 MFMA).
// MODE 0: A=x fp32 [B,N,C]; Nout=2304; scatter q/k/v -> [BH,N,D] bf16
// MODE 1: A=o1 bf16 [N,B,C]; Nout=768; -> fp32 [BH,N,D] (df)
// MODE 2: A=o2 bf16 [N,B,C]; Nout=768; -> fp32 [B,N,C] = d_out (df)
// ---------------------------------------------------------------------------
#define GK 768

template<int MODE>
__global__ __launch_bounds__(256, 2) void gemm_nt(
    const void* __restrict__ Araw, const float* __restrict__ W,
    const float* __restrict__ bias,
    u16* __restrict__ d0, u16* __restrict__ d1, u16* __restrict__ d2,
    float* __restrict__ df)
{
  constexpr int LDK = 72;  // pad 64 -> 72 elems: benign 2-way bank alias only
  __shared__ __align__(16) u16 sA[128 * LDK];
  __shared__ __align__(16) u16 sB[128 * LDK];
  const float* Af = (const float*)Araw;
  const u16*   Ab = (const u16*)Araw;
  const int tid  = threadIdx.x;
  const int m0   = blockIdx.y * 128, n0 = blockIdx.x * 128;
  const int w    = tid >> 6, lane = tid & 63, l16 = lane & 15, quad = lane >> 4;
  const int wm   = (w >> 1) * 64, wn = (w & 1) * 64;

  f32x4 acc[4][4] = {};
  const int sr = tid >> 3, sc = (tid & 7) * 8;   // 32 rows x 64 cols per pass

  for (int k0 = 0; k0 < GK; k0 += 64) {
    #pragma unroll
    for (int rr = 0; rr < 128; rr += 32) {
      const size_t arow = (size_t)(m0 + sr + rr) * GK + sc + k0;
      const size_t brow = (size_t)(n0 + sr + rr) * GK + sc + k0;
      if (MODE == 0) stage8_f32(sA + (sr + rr) * LDK + sc, Af + arow);
      else *(uint4*)(sA + (sr + rr) * LDK + sc) = *(const uint4*)(Ab + arow);
      stage8_f32(sB + (sr + rr) * LDK + sc, W + brow);
    }
    __syncthreads();
    #pragma unroll
    for (int ks = 0; ks < 64; ks += 32) {
      bf16x8 af[4], bfv[4];
      #pragma unroll
      for (int i = 0; i < 4; i++) af[i]  = ldfrag(sA + (wm + i * 16 + l16) * LDK + ks + quad * 8);
      #pragma unroll
      for (int i = 0; i < 4; i++) bfv[i] = ldfrag(sB + (wn + i * 16 + l16) * LDK + ks + quad * 8);
      #pragma unroll
      for (int mi = 0; mi < 4; mi++)
        #pragma unroll
        for (int ni = 0; ni < 4; ni++)
          acc[mi][ni] = __builtin_amdgcn_mfma_f32_16x16x32_bf16(af[mi], bfv[ni], acc[mi][ni], 0, 0, 0);
    }
    __syncthreads();
  }

  #pragma unroll
  for (int ni = 0; ni < 4; ni++) {
    const int gn = n0 + wn + ni * 16 + l16;
    const float bv = bias[gn];
    #pragma unroll
    for (int mi = 0; mi < 4; mi++) {
      #pragma unroll
      for (int r = 0; r < 4; r++) {
        const int gm = m0 + wm + mi * 16 + quad * 4 + r;
        const float v = acc[mi][ni][r] + bv;
        if (MODE == 0) {  // rows of x are m = b*2048 + nt
          const int which = gn / 768, c = gn - which * 768, h = c >> 6, d = c & 63;
          const int b = gm >> 11, nt = gm & 2047;
          u16* dst = (which == 0) ? d0 : (which == 1) ? d1 : d2;
          dst[(((size_t)(b * 12 + h)) * 2048 + nt) * 64 + d] = f2bf(v);
        } else if (MODE == 1) {  // rows m = nt*2 + b ([N,B,C])
          const int nt = gm >> 1, b = gm & 1, h = gn >> 6, d = gn & 63;
          df[(((size_t)(b * 12 + h)) * 2048 + nt) * 64 + d] = v;
        } else {                 // -> [B,N,C] fp32
          const int nt = gm >> 1, b = gm & 1;
          df[((size_t)b * 2048 + nt) * 768 + gn] = v;
        }
      }
    }
  }
}

// V [BH][N][64] bf16 -> VT [BH][64][N] bf16, 64x64 tiles through LDS.
__global__ __launch_bounds__(256) void transpose_v(const u16* __restrict__ in,
                                                   u16* __restrict__ out)
{
  constexpr int N = 2048;
  __shared__ __align__(16) u16 t[64 * 72];
  const int bh = blockIdx.y, n0 = blockIdx.x * 64;
  const int r = threadIdx.x >> 2, c0 = (threadIdx.x & 3) * 8;
  const u16* ip = in + ((size_t)bh * N + n0 + r) * 64;
  *(uint4*)(t + r * 72 + c0)      = *(const uint4*)(ip + c0);
  *(uint4*)(t + r * 72 + c0 + 32) = *(const uint4*)(ip + c0 + 32);
  __syncthreads();
  #pragma unroll
  for (int half = 0; half < 2; half++) {
    const int cc = c0 + half * 32;
    __align__(16) u16 tmp[8];
    #pragma unroll
    for (int i = 0; i < 8; i++) tmp[i] = t[(cc + i) * 72 + r];
    *(uint4*)(out + ((size_t)bh * 64 + r) * N + n0 + cc) = *(const uint4*)tmp;
  }
}

// ---------------------------------------------------------------------------
// Flash attention. Block = 64 Q-rows (4 waves x 16 rows), 64-wide K/V tiles.
// MODE 1: S = (Q.K^T)*0.125, plain softmax.
// MODE 2: S = (Q.K^T)*10, entries <0 masked (sentinel -1e30, exact-zero p).
// Q,K: [BH][N][64] bf16;  VT: [BH][64][N] bf16;  Out: [N][B][C] bf16.
// ---------------------------------------------------------------------------
template<int MODE>
__global__ __launch_bounds__(256, 2) void flash_attn(
    const u16* __restrict__ Qm, const u16* __restrict__ Km,
    const u16* __restrict__ VT, u16* __restrict__ Ob)
{
  constexpr int N = 2048;
  __shared__ __align__(16) u16 sQ[64 * 72];
  __shared__ __align__(16) u16 sK[64 * 72];
  __shared__ __align__(16) u16 sVT[64 * 72];
  __shared__ __align__(16) u16 sP[4][16 * 72];
  const int tid = threadIdx.x;
  const int bh = blockIdx.y, m0 = blockIdx.x * 64;
  const int b = bh / 12, h = bh % 12;
  const int w = tid >> 6, lane = tid & 63, l16 = lane & 15, quad = lane >> 4;

  const int sr_ = tid >> 2, sc_ = (tid & 3) * 8;
  {
    const u16* qp = Qm + ((size_t)bh * N + m0 + sr_) * 64;
    *(uint4*)(sQ + sr_ * 72 + sc_)      = *(const uint4*)(qp + sc_);
    *(uint4*)(sQ + sr_ * 72 + sc_ + 32) = *(const uint4*)(qp + sc_ + 32);
  }
  __syncthreads();
  bf16x8 qf0 = ldfrag(sQ + (w * 16 + l16) * 72 + quad * 8);
  bf16x8 qf1 = ldfrag(sQ + (w * 16 + l16) * 72 + 32 + quad * 8);

  float mrun[4], lrun[4];
  f32x4 oacc[4] = {};
  #pragma unroll
  for (int r = 0; r < 4; r++) { mrun[r] = -1e30f; lrun[r] = 0.f; }

  for (int j0 = 0; j0 < N; j0 += 64) {
    {
      const u16* kp = Km + ((size_t)bh * N + j0 + sr_) * 64;
      *(uint4*)(sK + sr_ * 72 + sc_)      = *(const uint4*)(kp + sc_);
      *(uint4*)(sK + sr_ * 72 + sc_ + 32) = *(const uint4*)(kp + sc_ + 32);
      const u16* vp = VT + ((size_t)bh * 64 + sr_) * N + j0;
      *(uint4*)(sVT + sr_ * 72 + sc_)      = *(const uint4*)(vp + sc_);
      *(uint4*)(sVT + sr_ * 72 + sc_ + 32) = *(const uint4*)(vp + sc_ + 32);
    }
    __syncthreads();

    f32x4 s[4];
    #pragma unroll
    for (int jt = 0; jt < 4; jt++) {
      f32x4 a = {};
      bf16x8 kf0 = ldfrag(sK + (jt * 16 + l16) * 72 + quad * 8);
      bf16x8 kf1 = ldfrag(sK + (jt * 16 + l16) * 72 + 32 + quad * 8);
      a = __builtin_amdgcn_mfma_f32_16x16x32_bf16(qf0, kf0, a, 0, 0, 0);
      a = __builtin_amdgcn_mfma_f32_16x16x32_bf16(qf1, kf1, a, 0, 0, 0);
      s[jt] = a * (MODE == 1 ? 0.125f : 10.f);
    }
    if (MODE == 2) {
      #pragma unroll
      for (int jt = 0; jt < 4; jt++)
        #pragma unroll
        for (int r = 0; r < 4; r++)
          if (s[jt][r] < 0.f) s[jt][r] = -1e30f;  // masked sentinel
    }

    float mnew[4], alpha[4], psum[4];
    #pragma unroll
    for (int r = 0; r < 4; r++) {
      float mx = fmaxf(fmaxf(s[0][r], s[1][r]), fmaxf(s[2][r], s[3][r]));
      #pragma unroll
      for (int off = 1; off < 16; off <<= 1) mx = fmaxf(mx, __shfl_xor(mx, off));
      mnew[r] = fmaxf(mrun[r], mx);
      alpha[r] = __expf(mrun[r] - mnew[r]);
      mrun[r] = mnew[r];
      psum[r] = 0.f;
    }
    #pragma unroll
    for (int jt = 0; jt < 4; jt++) {
      #pragma unroll
      for (int r = 0; r < 4; r++) {
        // explicit select: masked entries contribute exactly 0 even when the
        // whole row so far is masked (mnew == -1e30 -> alpha = exp(0) = 1).
        float p = (s[jt][r] <= -1e29f) ? 0.f : __expf(s[jt][r] - mnew[r]);
        psum[r] += p;
        sP[w][(quad * 4 + r) * 72 + jt * 16 + l16] = f2bf(p);
      }
    }
    #pragma unroll
    for (int r = 0; r < 4; r++) {
      #pragma unroll
      for (int off = 1; off < 16; off <<= 1) psum[r] += __shfl_xor(psum[r], off);
      lrun[r] = lrun[r] * alpha[r] + psum[r];
    }
    #pragma unroll
    for (int d4 = 0; d4 < 4; d4++)
      #pragma unroll
      for (int r = 0; r < 4; r++) oacc[d4][r] *= alpha[r];

    __syncthreads();  // make C-layout sP writes visible for A-layout re-read

    bf16x8 pf0 = ldfrag(sP[w] + l16 * 72 + quad * 8);
    bf16x8 pf1 = ldfrag(sP[w] + l16 * 72 + 32 + quad * 8);
    #pragma unroll
    for (int d4 = 0; d4 < 4; d4++) {
      bf16x8 v0 = ldfrag(sVT + (d4 * 16 + l16) * 72 + quad * 8);
      bf16x8 v1 = ldfrag(sVT + (d4 * 16 + l16) * 72 + 32 + quad * 8);
      oacc[d4] = __builtin_amdgcn_mfma_f32_16x16x32_bf16(pf0, v0, oacc[d4], 0, 0, 0);
      oacc[d4] = __builtin_amdgcn_mfma_f32_16x16x32_bf16(pf1, v1, oacc[d4], 0, 0, 0);
    }
    __syncthreads();
  }

  #pragma unroll
  for (int d4 = 0; d4 < 4; d4++) {
    #pragma unroll
    for (int r = 0; r < 4; r++) {
      const int n = m0 + w * 16 + quad * 4 + r;
      const float ov = oacc[d4][r] / fmaxf(lrun[r], 1e-20f);
      Ob[((size_t)n * 2 + b) * 768 + h * 64 + d4 * 16 + l16] = f2bf(ov);
    }
  }
}

// L2-normalize each 64-vector: in fp32 [BH*N][64] -> out bf16.
__global__ __launch_bounds__(256) void normalize_k(const float* __restrict__ in,
                                                   u16* __restrict__ out)
{
  const int row = blockIdx.x * 4 + (threadIdx.x >> 6);
  const int lane = threadIdx.x & 63;
  const size_t idx = (size_t)row * 64 + lane;
  float v = in[idx];
  float ss = v * v;
  #pragma unroll
  for (int off = 1; off < 64; off <<= 1) ss += __shfl_xor(ss, off);
  const float sc = 1.f / fmaxf(sqrtf(ss), 1e-12f);
  out[idx] = f2bf(v * sc);
}

extern "C" void kernel_launch(void* const* d_in, const int* in_sizes, int n_in,
                              void* d_out, int out_size, void* d_ws, size_t ws_size,
                              hipStream_t stream) {
  const float* x      = (const float*)d_in[0];
  const float* qkv_w  = (const float*)d_in[1];
  const float* qkv_b  = (const float*)d_in[2];
  const float* proj_w = (const float*)d_in[3];
  const float* proj_b = (const float*)d_in[4];
  float* out = (float*)d_out;

  const size_t SZ = (size_t)24 * 2048 * 64;  // elems per [BH,N,D] buffer
  char* ws = (char*)d_ws;
  u16* qb  = (u16*)(ws);             // later reused as st (sim_tokens)
  u16* kb  = (u16*)(ws + SZ * 2);    // kb..vb region later reused as p1 (fp32)
  u16* vb  = (u16*)(ws + SZ * 4);
  u16* vtb = (u16*)(ws + SZ * 6);
  u16* o1  = (u16*)(ws + SZ * 8);    // later reused as o2
  float* p1 = (float*)(ws + SZ * 2);
  u16* st  = (u16*)(ws);
  u16* o2  = (u16*)(ws + SZ * 8);
  // total ws use: SZ*10 bytes = 31.5 MB

  // 1. QKV projection -> q,k,v [BH,N,D] bf16
  gemm_nt<0><<<dim3(18, 32), 256, 0, stream>>>(x, qkv_w, qkv_b, qb, kb, vb, nullptr);
  // 2. V -> V^T [BH,D,N]
  transpose_v<<<dim3(32, 24), 256, 0, stream>>>(vb, vtb);
  // 3. stage-1 attention -> o1 in [N,B,C] bf16
  flash_attn<1><<<dim3(32, 24), 256, 0, stream>>>(qb, kb, vtb, o1);
  // 4. proj1 -> p1 fp32 [BH,N,D]
  gemm_nt<1><<<dim3(6, 32), 256, 0, stream>>>(o1, proj_w, proj_b, nullptr, nullptr, nullptr, p1);
  // 5. L2 normalize -> sim_tokens bf16
  normalize_k<<<dim3(12288), 256, 0, stream>>>(p1, st);
  // 6. stage-2 masked self-correlation attention -> o2 [N,B,C] bf16
  flash_attn<2><<<dim3(32, 24), 256, 0, stream>>>(st, st, vtb, o2);
  // 7. proj2 -> d_out fp32 [B,N,C]
  gemm_nt<2><<<dim3(6, 32), 256, 0, stream>>>(o2, proj_w, proj_b, nullptr, nullptr, nullptr, out);
}

// Round 3
// 353.540 us; speedup vs baseline: 1.0793x; 1.0793x over previous
//
#include <hip/hip_runtime.h>

typedef unsigned short u16;
typedef __bf16 bf16_t;
typedef bf16_t bf16x8 __attribute__((ext_vector_type(8)));
typedef float f32x4 __attribute__((ext_vector_type(4)));

static __device__ __forceinline__ u16 f2bf(float f) {
  unsigned u = __builtin_bit_cast(unsigned, f);
  u += 0x7FFFu + ((u >> 16) & 1u);
  return (u16)(u >> 16);
}
static __device__ __forceinline__ bf16x8 ldfrag(const u16* p) {
  return __builtin_bit_cast(bf16x8, *(const uint4*)p);
}

// ---------------------------------------------------------------------------
// One-shot fp32 -> bf16 conversion of x, qkv_w, proj_w (concatenated ranges).
// ---------------------------------------------------------------------------
#define XSZ 3145728   // 2*2048*768
#define QWSZ 1769472  // 2304*768
#define PWSZ 589824   // 768*768

__global__ __launch_bounds__(256) void convert_all(
    const float* __restrict__ x, const float* __restrict__ qw,
    const float* __restrict__ pw, u16* __restrict__ xb,
    u16* __restrict__ qwb, u16* __restrict__ pwb)
{
  const int i = (blockIdx.x * 256 + threadIdx.x) * 8;
  const float* src; u16* dst; int off;
  if (i < XSZ) { src = x; dst = xb; off = i; }
  else if (i < XSZ + QWSZ) { src = qw; dst = qwb; off = i - XSZ; }
  else { src = pw; dst = pwb; off = i - (XSZ + QWSZ); }
  float4 a = *(const float4*)(src + off), b = *(const float4*)(src + off + 4);
  u16 t[8] = {f2bf(a.x), f2bf(a.y), f2bf(a.z), f2bf(a.w),
              f2bf(b.x), f2bf(b.y), f2bf(b.z), f2bf(b.w)};
  *(uint4*)(dst + off) = *(const uint4*)t;
}

// ---------------------------------------------------------------------------
// NT GEMM (all-bf16 inputs): C[m,n] = sum_k A[m,k] W[n,k] + bias[n]. K=768.
// MODE 0: BM=128, A=xb [B,N,C]; scatter q/k/v -> [BH,N,D] bf16
// MODE 1: BM=64,  A=o1 [N,B,C]; fused L2-normalize -> st bf16 [BH,N,D]
// MODE 2: BM=64,  A=o2 [N,B,C]; -> fp32 d_out [B,N,C]
// ---------------------------------------------------------------------------
template<int MODE>
__global__ __launch_bounds__(256, 2) void gemm_nt(
    const u16* __restrict__ A, const u16* __restrict__ W,
    const float* __restrict__ bias,
    u16* __restrict__ d0, u16* __restrict__ d1, u16* __restrict__ d2,
    float* __restrict__ df)
{
  constexpr int BM = (MODE == 0) ? 128 : 64;
  constexpr int MI = (MODE == 0) ? 4 : 2;
  constexpr int LDK = 72;
  __shared__ __align__(16) u16 sA[BM * LDK];
  __shared__ __align__(16) u16 sB[128 * LDK];
  const int tid = threadIdx.x;
  const int m0 = blockIdx.y * BM, n0 = blockIdx.x * 128;
  const int w = tid >> 6, lane = tid & 63, l16 = lane & 15, quad = lane >> 4;
  const int wm = (w >> 1) * (BM / 2), wn = (w & 1) * 64;

  f32x4 acc[MI][4] = {};
  const int sr = tid >> 3, sc = (tid & 7) * 8;  // 32 rows x 64 cols per pass

  for (int k0 = 0; k0 < 768; k0 += 64) {
    #pragma unroll
    for (int rr = 0; rr < BM; rr += 32)
      *(uint4*)(sA + (sr + rr) * LDK + sc) =
          *(const uint4*)(A + (size_t)(m0 + sr + rr) * 768 + k0 + sc);
    #pragma unroll
    for (int rr = 0; rr < 128; rr += 32)
      *(uint4*)(sB + (sr + rr) * LDK + sc) =
          *(const uint4*)(W + (size_t)(n0 + sr + rr) * 768 + k0 + sc);
    __syncthreads();
    #pragma unroll
    for (int ks = 0; ks < 64; ks += 32) {
      bf16x8 af[MI], bfv[4];
      #pragma unroll
      for (int i = 0; i < MI; i++)
        af[i] = ldfrag(sA + (wm + i * 16 + l16) * LDK + ks + quad * 8);
      #pragma unroll
      for (int i = 0; i < 4; i++)
        bfv[i] = ldfrag(sB + (wn + i * 16 + l16) * LDK + ks + quad * 8);
      #pragma unroll
      for (int mi = 0; mi < MI; mi++)
        #pragma unroll
        for (int ni = 0; ni < 4; ni++)
          acc[mi][ni] = __builtin_amdgcn_mfma_f32_16x16x32_bf16(af[mi], bfv[ni], acc[mi][ni], 0, 0, 0);
    }
    __syncthreads();
  }

  if (MODE == 0) {
    #pragma unroll
    for (int ni = 0; ni < 4; ni++) {
      const int gn = n0 + wn + ni * 16 + l16;
      const float bv = bias[gn];
      #pragma unroll
      for (int mi = 0; mi < MI; mi++) {
        #pragma unroll
        for (int r = 0; r < 4; r++) {
          const int gm = m0 + wm + mi * 16 + quad * 4 + r;
          const float v = acc[mi][ni][r] + bv;
          const int which = gn / 768, c = gn - which * 768, h = c >> 6, d = c & 63;
          const int b = gm >> 11, nt = gm & 2047;
          u16* dst = (which == 0) ? d0 : (which == 1) ? d1 : d2;
          dst[(((size_t)(b * 12 + h)) * 2048 + nt) * 64 + d] = f2bf(v);
        }
      }
    }
  } else if (MODE == 1) {
    // fused F.normalize: wave's 64-col span = one head (n0+wn is 64-aligned)
    #pragma unroll
    for (int mi = 0; mi < MI; mi++) {
      #pragma unroll
      for (int r = 0; r < 4; r++) {
        float v[4]; float ss = 0.f;
        #pragma unroll
        for (int ni = 0; ni < 4; ni++) {
          v[ni] = acc[mi][ni][r] + bias[n0 + wn + ni * 16 + l16];
          ss += v[ni] * v[ni];
        }
        #pragma unroll
        for (int off = 1; off < 16; off <<= 1) ss += __shfl_xor(ss, off);
        const float scl = 1.f / fmaxf(sqrtf(ss), 1e-12f);
        const int gm = m0 + wm + mi * 16 + quad * 4 + r;
        const int nt = gm >> 1, b = gm & 1;
        #pragma unroll
        for (int ni = 0; ni < 4; ni++) {
          const int gn = n0 + wn + ni * 16 + l16, h = gn >> 6, d = gn & 63;
          d0[(((size_t)(b * 12 + h)) * 2048 + nt) * 64 + d] = f2bf(v[ni] * scl);
        }
      }
    }
  } else {
    #pragma unroll
    for (int ni = 0; ni < 4; ni++) {
      const int gn = n0 + wn + ni * 16 + l16;
      const float bv = bias[gn];
      #pragma unroll
      for (int mi = 0; mi < MI; mi++) {
        #pragma unroll
        for (int r = 0; r < 4; r++) {
          const int gm = m0 + wm + mi * 16 + quad * 4 + r;
          const int nt = gm >> 1, b = gm & 1;
          df[((size_t)b * 2048 + nt) * 768 + gn] = acc[mi][ni][r] + bv;
        }
      }
    }
  }
}

// V [BH][N][64] bf16 -> VT [BH][64][N] bf16, 64x64 tiles through LDS.
__global__ __launch_bounds__(256) void transpose_v(const u16* __restrict__ in,
                                                   u16* __restrict__ out)
{
  constexpr int N = 2048;
  __shared__ __align__(16) u16 t[64 * 72];
  const int bh = blockIdx.y, n0 = blockIdx.x * 64;
  const int r = threadIdx.x >> 2, c0 = (threadIdx.x & 3) * 8;
  const u16* ip = in + ((size_t)bh * N + n0 + r) * 64;
  *(uint4*)(t + r * 72 + c0)      = *(const uint4*)(ip + c0);
  *(uint4*)(t + r * 72 + c0 + 32) = *(const uint4*)(ip + c0 + 32);
  __syncthreads();
  #pragma unroll
  for (int half = 0; half < 2; half++) {
    const int cc = c0 + half * 32;
    __align__(16) u16 tmp[8];
    #pragma unroll
    for (int i = 0; i < 8; i++) tmp[i] = t[(cc + i) * 72 + r];
    *(uint4*)(out + ((size_t)bh * 64 + r) * N + n0 + cc) = *(const uint4*)tmp;
  }
}

// ---------------------------------------------------------------------------
// Flash attention, double-buffered K/V, ONE block barrier per j-tile.
// MODE 1: S = (Q.K^T)*0.125, plain softmax.
// MODE 2: S = (Q.K^T)*10, entries <0 masked (sentinel -1e30, exact-zero p).
// ---------------------------------------------------------------------------
template<int MODE>
__global__ __launch_bounds__(256, 3) void flash_attn(
    const u16* __restrict__ Qm, const u16* __restrict__ Km,
    const u16* __restrict__ VT, u16* __restrict__ Ob)
{
  constexpr int N = 2048;
  constexpr int LP = 76;  // sQ/sP stride: 152 B -> conflict-free P writes
  __shared__ __align__(16) u16 sQ[64 * LP];   // overlaid by sP after q-frag load
  __shared__ __align__(16) u16 sK[2][64 * 72];
  __shared__ __align__(16) u16 sVT[2][64 * 72];
  const int tid = threadIdx.x;
  const int bh = blockIdx.y, m0 = blockIdx.x * 64;
  const int b = bh / 12, h = bh % 12;
  const int w = tid >> 6, lane = tid & 63, l16 = lane & 15, quad = lane >> 4;
  u16* sPw = sQ + w * 16 * LP;

  const int sr_ = tid >> 2, sc_ = (tid & 3) * 8;
  const u16* kbase = Km + (size_t)bh * N * 64;
  const u16* vbase = VT + (size_t)bh * 64 * N;
  {
    const u16* qp = Qm + ((size_t)bh * N + m0 + sr_) * 64;
    *(uint4*)(sQ + sr_ * LP + sc_)      = *(const uint4*)(qp + sc_);
    *(uint4*)(sQ + sr_ * LP + sc_ + 32) = *(const uint4*)(qp + sc_ + 32);
    const u16* kp = kbase + (size_t)sr_ * 64;
    *(uint4*)(sK[0] + sr_ * 72 + sc_)      = *(const uint4*)(kp + sc_);
    *(uint4*)(sK[0] + sr_ * 72 + sc_ + 32) = *(const uint4*)(kp + sc_ + 32);
    const u16* vp = vbase + (size_t)sr_ * N;
    *(uint4*)(sVT[0] + sr_ * 72 + sc_)      = *(const uint4*)(vp + sc_);
    *(uint4*)(sVT[0] + sr_ * 72 + sc_ + 32) = *(const uint4*)(vp + sc_ + 32);
  }
  __syncthreads();
  bf16x8 qf0 = ldfrag(sQ + (w * 16 + l16) * LP + quad * 8);
  bf16x8 qf1 = ldfrag(sQ + (w * 16 + l16) * LP + 32 + quad * 8);
  asm volatile("s_waitcnt lgkmcnt(0)" ::: "memory");  // qf in regs before sP overlays

  float mrun[4], lrun[4];
  f32x4 oacc[4] = {};
  #pragma unroll
  for (int r = 0; r < 4; r++) { mrun[r] = -1e30f; lrun[r] = 0.f; }

  for (int it = 0; it < 32; it++) {
    const int buf = it & 1;
    const u16* sKb = sK[buf];
    const u16* sVb = sVT[buf];
    u16* sKn = sK[buf ^ 1];
    u16* sVn = sVT[buf ^ 1];

    // issue next tile's global loads now; LDS-write them after softmax
    uint4 pk0, pk1, pv0, pv1;
    const bool pre = (it + 1 < 32);
    if (pre) {
      const int j1 = (it + 1) * 64;
      const u16* kp = kbase + (size_t)(j1 + sr_) * 64;
      pk0 = *(const uint4*)(kp + sc_);
      pk1 = *(const uint4*)(kp + sc_ + 32);
      const u16* vp = vbase + (size_t)sr_ * N + j1;
      pv0 = *(const uint4*)(vp + sc_);
      pv1 = *(const uint4*)(vp + sc_ + 32);
    }

    f32x4 s[4];
    #pragma unroll
    for (int jt = 0; jt < 4; jt++) {
      f32x4 a = {};
      bf16x8 kf0 = ldfrag(sKb + (jt * 16 + l16) * 72 + quad * 8);
      bf16x8 kf1 = ldfrag(sKb + (jt * 16 + l16) * 72 + 32 + quad * 8);
      a = __builtin_amdgcn_mfma_f32_16x16x32_bf16(qf0, kf0, a, 0, 0, 0);
      a = __builtin_amdgcn_mfma_f32_16x16x32_bf16(qf1, kf1, a, 0, 0, 0);
      s[jt] = a * (MODE == 1 ? 0.125f : 10.f);
    }
    if (MODE == 2) {
      #pragma unroll
      for (int jt = 0; jt < 4; jt++)
        #pragma unroll
        for (int r = 0; r < 4; r++)
          if (s[jt][r] < 0.f) s[jt][r] = -1e30f;
    }

    float mnew[4], alpha[4], psum[4];
    #pragma unroll
    for (int r = 0; r < 4; r++) {
      float mx = fmaxf(fmaxf(s[0][r], s[1][r]), fmaxf(s[2][r], s[3][r]));
      #pragma unroll
      for (int off = 1; off < 16; off <<= 1) mx = fmaxf(mx, __shfl_xor(mx, off));
      mnew[r] = fmaxf(mrun[r], mx);
      alpha[r] = __expf(mrun[r] - mnew[r]);
      mrun[r] = mnew[r];
      psum[r] = 0.f;
    }
    #pragma unroll
    for (int jt = 0; jt < 4; jt++) {
      #pragma unroll
      for (int r = 0; r < 4; r++) {
        float p = (MODE == 2 && s[jt][r] <= -1e29f) ? 0.f
                                                    : __expf(s[jt][r] - mnew[r]);
        // truncate to bf16; use the SAME truncated value in psum so the
        // numerator/denominator truncation bias cancels in O = sum(pV)/sum(p)
        unsigned pu = __builtin_bit_cast(unsigned, p) & 0xFFFF0000u;
        psum[r] += __builtin_bit_cast(float, pu);
        sPw[(quad * 4 + r) * LP + jt * 16 + l16] = (u16)(pu >> 16);
      }
    }
    #pragma unroll
    for (int r = 0; r < 4; r++) {
      #pragma unroll
      for (int off = 1; off < 16; off <<= 1) psum[r] += __shfl_xor(psum[r], off);
      lrun[r] = lrun[r] * alpha[r] + psum[r];
    }
    #pragma unroll
    for (int d4 = 0; d4 < 4; d4++)
      #pragma unroll
      for (int r = 0; r < 4; r++) oacc[d4][r] *= alpha[r];

    // wave-local drain: sP writes complete before A-layout re-read
    asm volatile("s_waitcnt lgkmcnt(0)" ::: "memory");
    bf16x8 pf0 = ldfrag(sPw + l16 * LP + quad * 8);
    bf16x8 pf1 = ldfrag(sPw + l16 * LP + 32 + quad * 8);

    if (pre) {  // LDS-write the prefetched tile (other buffer, no reader yet)
      *(uint4*)(sKn + sr_ * 72 + sc_)      = pk0;
      *(uint4*)(sKn + sr_ * 72 + sc_ + 32) = pk1;
      *(uint4*)(sVn + sr_ * 72 + sc_)      = pv0;
      *(uint4*)(sVn + sr_ * 72 + sc_ + 32) = pv1;
    }

    #pragma unroll
    for (int d4 = 0; d4 < 4; d4++) {
      bf16x8 v0 = ldfrag(sVb + (d4 * 16 + l16) * 72 + quad * 8);
      bf16x8 v1 = ldfrag(sVb + (d4 * 16 + l16) * 72 + 32 + quad * 8);
      oacc[d4] = __builtin_amdgcn_mfma_f32_16x16x32_bf16(pf0, v0, oacc[d4], 0, 0, 0);
      oacc[d4] = __builtin_amdgcn_mfma_f32_16x16x32_bf16(pf1, v1, oacc[d4], 0, 0, 0);
    }
    __syncthreads();  // single per-iter barrier: buf consumed, next buf visible
  }

  #pragma unroll
  for (int d4 = 0; d4 < 4; d4++) {
    #pragma unroll
    for (int r = 0; r < 4; r++) {
      const int n = m0 + w * 16 + quad * 4 + r;
      const float ov = oacc[d4][r] / fmaxf(lrun[r], 1e-20f);
      Ob[((size_t)n * 2 + b) * 768 + h * 64 + d4 * 16 + l16] = f2bf(ov);
    }
  }
}

extern "C" void kernel_launch(void* const* d_in, const int* in_sizes, int n_in,
                              void* d_out, int out_size, void* d_ws, size_t ws_size,
                              hipStream_t stream) {
  const float* x      = (const float*)d_in[0];
  const float* qkv_w  = (const float*)d_in[1];
  const float* qkv_b  = (const float*)d_in[2];
  const float* proj_w = (const float*)d_in[3];
  const float* proj_b = (const float*)d_in[4];
  float* out = (float*)d_out;

  char* ws = (char*)d_ws;
  // region 0 (6.29 MB): xb, then vtb (xb dead after QKV gemm)
  u16* xb  = (u16*)ws;
  u16* vtb = (u16*)ws;
  size_t off = (size_t)XSZ * 2;
  u16* qwb = (u16*)(ws + off); off += (size_t)QWSZ * 2;
  u16* pwb = (u16*)(ws + off); off += (size_t)PWSZ * 2;
  u16* qb  = (u16*)(ws + off); off += (size_t)XSZ * 2;
  u16* kb  = (u16*)(ws + off);            // st overlays kb (kb dead after flash1)
  u16* st  = kb;               off += (size_t)XSZ * 2;
  u16* vb  = (u16*)(ws + off);            // o1/o2 overlay vb (vb dead after transpose)
  u16* o1  = vb; u16* o2 = vb;
  // total ws use ~29.9 MB

  convert_all<<<2688, 256, 0, stream>>>(x, qkv_w, proj_w, xb, qwb, pwb);
  gemm_nt<0><<<dim3(18, 32), 256, 0, stream>>>(xb, qwb, qkv_b, qb, kb, vb, nullptr);
  transpose_v<<<dim3(32, 24), 256, 0, stream>>>(vb, vtb);
  flash_attn<1><<<dim3(32, 24), 256, 0, stream>>>(qb, kb, vtb, o1);
  gemm_nt<1><<<dim3(6, 64), 256, 0, stream>>>(o1, pwb, proj_b, st, nullptr, nullptr, nullptr);
  flash_attn<2><<<dim3(32, 24), 256, 0, stream>>>(st, st, vtb, o2);
  gemm_nt<2><<<dim3(6, 64), 256, 0, stream>>>(o2, pwb, proj_b, nullptr, nullptr, nullptr, out);
}

// Round 4
// 257.907 us; speedup vs baseline: 1.4795x; 1.3708x over previous
//
#include <hip/hip_runtime.h>

typedef unsigned short u16;
typedef __bf16 bf16_t;
typedef bf16_t bf16x8 __attribute__((ext_vector_type(8)));
typedef float f32x4 __attribute__((ext_vector_type(4)));

static __device__ __forceinline__ u16 f2bf(float f) {
  unsigned u = __builtin_bit_cast(unsigned, f);
  u += 0x7FFFu + ((u >> 16) & 1u);
  return (u16)(u >> 16);
}
static __device__ __forceinline__ bf16x8 ldfrag(const u16* p) {
  return __builtin_bit_cast(bf16x8, *(const uint4*)p);
}
static __device__ __forceinline__ float fexp2(float x) {
#if __has_builtin(__builtin_amdgcn_exp2f)
  return __builtin_amdgcn_exp2f(x);
#else
  return __expf(x * 0.69314718056f);
#endif
}

// ---------------------------------------------------------------------------
// One-shot fp32 -> bf16 conversion of x, qkv_w, proj_w (concatenated ranges).
// ---------------------------------------------------------------------------
#define XSZ 3145728   // 2*2048*768
#define QWSZ 1769472  // 2304*768
#define PWSZ 589824   // 768*768

__global__ __launch_bounds__(256) void convert_all(
    const float* __restrict__ x, const float* __restrict__ qw,
    const float* __restrict__ pw, u16* __restrict__ xb,
    u16* __restrict__ qwb, u16* __restrict__ pwb)
{
  const int i = (blockIdx.x * 256 + threadIdx.x) * 8;
  const float* src; u16* dst; int off;
  if (i < XSZ) { src = x; dst = xb; off = i; }
  else if (i < XSZ + QWSZ) { src = qw; dst = qwb; off = i - XSZ; }
  else { src = pw; dst = pwb; off = i - (XSZ + QWSZ); }
  float4 a = *(const float4*)(src + off), b = *(const float4*)(src + off + 4);
  u16 t[8] = {f2bf(a.x), f2bf(a.y), f2bf(a.z), f2bf(a.w),
              f2bf(b.x), f2bf(b.y), f2bf(b.z), f2bf(b.w)};
  *(uint4*)(dst + off) = *(const uint4*)t;
}

// ---------------------------------------------------------------------------
// NT GEMM (all-bf16 inputs): C[m,n] = sum_k A[m,k] W[n,k] + bias[n]. K=768.
// MODE 0: BM=128, A=xb [B,N,C]; scatter q/k/v -> [BH,N,D] bf16
// MODE 1: BM=64,  A=o1 [N,B,C]; fused L2-normalize -> st bf16 [BH,N,D]
// MODE 2: BM=64,  A=o2 [N,B,C]; -> fp32 d_out [B,N,C]
// ---------------------------------------------------------------------------
template<int MODE>
__global__ __launch_bounds__(256, 2) void gemm_nt(
    const u16* __restrict__ A, const u16* __restrict__ W,
    const float* __restrict__ bias,
    u16* __restrict__ d0, u16* __restrict__ d1, u16* __restrict__ d2,
    float* __restrict__ df)
{
  constexpr int BM = (MODE == 0) ? 128 : 64;
  constexpr int MI = (MODE == 0) ? 4 : 2;
  constexpr int LDK = 72;
  __shared__ __align__(16) u16 sA[BM * LDK];
  __shared__ __align__(16) u16 sB[128 * LDK];
  const int tid = threadIdx.x;
  const int m0 = blockIdx.y * BM, n0 = blockIdx.x * 128;
  const int w = tid >> 6, lane = tid & 63, l16 = lane & 15, quad = lane >> 4;
  const int wm = (w >> 1) * (BM / 2), wn = (w & 1) * 64;

  f32x4 acc[MI][4] = {};
  const int sr = tid >> 3, sc = (tid & 7) * 8;  // 32 rows x 64 cols per pass

  for (int k0 = 0; k0 < 768; k0 += 64) {
    #pragma unroll
    for (int rr = 0; rr < BM; rr += 32)
      *(uint4*)(sA + (sr + rr) * LDK + sc) =
          *(const uint4*)(A + (size_t)(m0 + sr + rr) * 768 + k0 + sc);
    #pragma unroll
    for (int rr = 0; rr < 128; rr += 32)
      *(uint4*)(sB + (sr + rr) * LDK + sc) =
          *(const uint4*)(W + (size_t)(n0 + sr + rr) * 768 + k0 + sc);
    __syncthreads();
    #pragma unroll
    for (int ks = 0; ks < 64; ks += 32) {
      bf16x8 af[MI], bfv[4];
      #pragma unroll
      for (int i = 0; i < MI; i++)
        af[i] = ldfrag(sA + (wm + i * 16 + l16) * LDK + ks + quad * 8);
      #pragma unroll
      for (int i = 0; i < 4; i++)
        bfv[i] = ldfrag(sB + (wn + i * 16 + l16) * LDK + ks + quad * 8);
      #pragma unroll
      for (int mi = 0; mi < MI; mi++)
        #pragma unroll
        for (int ni = 0; ni < 4; ni++)
          acc[mi][ni] = __builtin_amdgcn_mfma_f32_16x16x32_bf16(af[mi], bfv[ni], acc[mi][ni], 0, 0, 0);
    }
    __syncthreads();
  }

  if (MODE == 0) {
    #pragma unroll
    for (int ni = 0; ni < 4; ni++) {
      const int gn = n0 + wn + ni * 16 + l16;
      const float bv = bias[gn];
      #pragma unroll
      for (int mi = 0; mi < MI; mi++) {
        #pragma unroll
        for (int r = 0; r < 4; r++) {
          const int gm = m0 + wm + mi * 16 + quad * 4 + r;
          const float v = acc[mi][ni][r] + bv;
          const int which = gn / 768, c = gn - which * 768, h = c >> 6, d = c & 63;
          const int b = gm >> 11, nt = gm & 2047;
          u16* dst = (which == 0) ? d0 : (which == 1) ? d1 : d2;
          dst[(((size_t)(b * 12 + h)) * 2048 + nt) * 64 + d] = f2bf(v);
        }
      }
    }
  } else if (MODE == 1) {
    // fused F.normalize: wave's 64-col span = one head (n0+wn is 64-aligned)
    #pragma unroll
    for (int mi = 0; mi < MI; mi++) {
      #pragma unroll
      for (int r = 0; r < 4; r++) {
        float v[4]; float ss = 0.f;
        #pragma unroll
        for (int ni = 0; ni < 4; ni++) {
          v[ni] = acc[mi][ni][r] + bias[n0 + wn + ni * 16 + l16];
          ss += v[ni] * v[ni];
        }
        #pragma unroll
        for (int off = 1; off < 16; off <<= 1) ss += __shfl_xor(ss, off);
        const float scl = 1.f / fmaxf(sqrtf(ss), 1e-12f);
        const int gm = m0 + wm + mi * 16 + quad * 4 + r;
        const int nt = gm >> 1, b = gm & 1;
        #pragma unroll
        for (int ni = 0; ni < 4; ni++) {
          const int gn = n0 + wn + ni * 16 + l16, h = gn >> 6, d = gn & 63;
          d0[(((size_t)(b * 12 + h)) * 2048 + nt) * 64 + d] = f2bf(v[ni] * scl);
        }
      }
    }
  } else {
    #pragma unroll
    for (int ni = 0; ni < 4; ni++) {
      const int gn = n0 + wn + ni * 16 + l16;
      const float bv = bias[gn];
      #pragma unroll
      for (int mi = 0; mi < MI; mi++) {
        #pragma unroll
        for (int r = 0; r < 4; r++) {
          const int gm = m0 + wm + mi * 16 + quad * 4 + r;
          const int nt = gm >> 1, b = gm & 1;
          df[((size_t)b * 2048 + nt) * 768 + gn] = acc[mi][ni][r] + bv;
        }
      }
    }
  }
}

// V [BH][N][64] bf16 -> VT [BH][64][N] bf16, 64x64 tiles through LDS.
__global__ __launch_bounds__(256) void transpose_v(const u16* __restrict__ in,
                                                   u16* __restrict__ out)
{
  constexpr int N = 2048;
  __shared__ __align__(16) u16 t[64 * 72];
  const int bh = blockIdx.y, n0 = blockIdx.x * 64;
  const int r = threadIdx.x >> 2, c0 = (threadIdx.x & 3) * 8;
  const u16* ip = in + ((size_t)bh * N + n0 + r) * 64;
  *(uint4*)(t + r * 72 + c0)      = *(const uint4*)(ip + c0);
  *(uint4*)(t + r * 72 + c0 + 32) = *(const uint4*)(ip + c0 + 32);
  __syncthreads();
  #pragma unroll
  for (int half = 0; half < 2; half++) {
    const int cc = c0 + half * 32;
    __align__(16) u16 tmp[8];
    #pragma unroll
    for (int i = 0; i < 8; i++) tmp[i] = t[(cc + i) * 72 + r];
    *(uint4*)(out + ((size_t)bh * 64 + r) * N + n0 + cc) = *(const uint4*)tmp;
  }
}

// ---------------------------------------------------------------------------
// Flash attention, S^T formulation (lane = query), double-buffered K/V,
// one block barrier per j-tile. exp in base-2 domain (scale folds log2e).
// MODE 1: scores * 0.125;  MODE 2: scores * 10, entries < 0 masked.
// ---------------------------------------------------------------------------
template<int MODE>
__global__ __launch_bounds__(256, 3) void flash_attn(
    const u16* __restrict__ Qm, const u16* __restrict__ Km,
    const u16* __restrict__ VT, u16* __restrict__ Ob)
{
  constexpr int N = 2048;
  constexpr int LU = 72;  // sQ/sP row stride (u16): 16B-aligned rows
  __shared__ __align__(16) u16 sU[64 * LU];   // Q staging, then per-wave P
  __shared__ __align__(16) u16 sK[2][64 * 72];
  __shared__ __align__(16) u16 sVT[2][64 * 72];
  const int tid = threadIdx.x;
  const int bh = blockIdx.y, m0 = blockIdx.x * 64;
  const int b = bh / 12, h = bh % 12;
  const int w = tid >> 6, lane = tid & 63, l16 = lane & 15, quad = lane >> 4;
  u16* sPw = sU + w * 16 * LU;  // 16 query rows x 64 key cols (stride LU)

  constexpr float SC = (MODE == 1) ? 0.18033688011112042f   // 0.125*log2(e)
                                   : 14.426950408889634f;   // 10*log2(e)

  const int sr_ = tid >> 2, sc_ = (tid & 3) * 8;
  const u16* kbase = Km + (size_t)bh * N * 64;
  const u16* vbase = VT + (size_t)bh * 64 * N;
  {
    const u16* qp = Qm + ((size_t)bh * N + m0 + sr_) * 64;
    *(uint4*)(sU + sr_ * LU + sc_)      = *(const uint4*)(qp + sc_);
    *(uint4*)(sU + sr_ * LU + sc_ + 32) = *(const uint4*)(qp + sc_ + 32);
    const u16* kp = kbase + (size_t)sr_ * 64;
    *(uint4*)(sK[0] + sr_ * 72 + sc_)      = *(const uint4*)(kp + sc_);
    *(uint4*)(sK[0] + sr_ * 72 + sc_ + 32) = *(const uint4*)(kp + sc_ + 32);
    const u16* vp = vbase + (size_t)sr_ * N;
    *(uint4*)(sVT[0] + sr_ * 72 + sc_)      = *(const uint4*)(vp + sc_);
    *(uint4*)(sVT[0] + sr_ * 72 + sc_ + 32) = *(const uint4*)(vp + sc_ + 32);
  }
  __syncthreads();
  // each wave reads ONLY its own 16 rows (the ones it overlays with P later)
  bf16x8 qf0 = ldfrag(sU + (w * 16 + l16) * LU + quad * 8);
  bf16x8 qf1 = ldfrag(sU + (w * 16 + l16) * LU + 32 + quad * 8);
  asm volatile("s_waitcnt lgkmcnt(0)" ::: "memory");

  float mrun = -1e30f, lrun = 0.f;
  f32x4 oacc[4] = {};

  for (int it = 0; it < 32; it++) {
    const int buf = it & 1;
    const u16* sKb = sK[buf];
    const u16* sVb = sVT[buf];
    u16* sKn = sK[buf ^ 1];
    u16* sVn = sVT[buf ^ 1];

    // issue next tile's global loads now; LDS-write them later
    uint4 pk0, pk1, pv0, pv1;
    const bool pre = (it + 1 < 32);
    if (pre) {
      const int j1 = (it + 1) * 64;
      const u16* kp = kbase + (size_t)(j1 + sr_) * 64;
      pk0 = *(const uint4*)(kp + sc_);
      pk1 = *(const uint4*)(kp + sc_ + 32);
      const u16* vp = vbase + (size_t)sr_ * N + j1;
      pv0 = *(const uint4*)(vp + sc_);
      pv1 = *(const uint4*)(vp + sc_ + 32);
    }

    // S^T tiles: D[m=key][n=query] = K . Q^T  (operands swapped)
    f32x4 s[4];
    #pragma unroll
    for (int jt = 0; jt < 4; jt++) {
      f32x4 a = {};
      bf16x8 kf0 = ldfrag(sKb + (jt * 16 + l16) * 72 + quad * 8);
      bf16x8 kf1 = ldfrag(sKb + (jt * 16 + l16) * 72 + 32 + quad * 8);
      a = __builtin_amdgcn_mfma_f32_16x16x32_bf16(kf0, qf0, a, 0, 0, 0);
      a = __builtin_amdgcn_mfma_f32_16x16x32_bf16(kf1, qf1, a, 0, 0, 0);
      s[jt] = a * SC;  // base-2 domain
    }
    if (MODE == 2) {
      #pragma unroll
      for (int jt = 0; jt < 4; jt++)
        #pragma unroll
        for (int r = 0; r < 4; r++)
          if (s[jt][r] < 0.f) s[jt][r] = -1e30f;
    }

    // per-lane (= per-query) softmax state; keys: 16 in-lane + cross-quad
    float mx = s[0][0];
    #pragma unroll
    for (int jt = 0; jt < 4; jt++)
      #pragma unroll
      for (int r = 0; r < 4; r++) mx = fmaxf(mx, s[jt][r]);
    mx = fmaxf(mx, __shfl_xor(mx, 16));
    mx = fmaxf(mx, __shfl_xor(mx, 32));
    const float mnew = fmaxf(mrun, mx);
    const float alpha = fexp2(mrun - mnew);
    mrun = mnew;

    float psum = 0.f;
    #pragma unroll
    for (int jt = 0; jt < 4; jt++) {
      unsigned pu[4];
      #pragma unroll
      for (int r = 0; r < 4; r++) {
        float p = (MODE == 2 && s[jt][r] <= -1e29f) ? 0.f
                                                    : fexp2(s[jt][r] - mnew);
        // truncate to bf16; use the truncated value in psum too, so the
        // truncation bias cancels in O = sum(pV)/sum(p)
        pu[r] = __builtin_bit_cast(unsigned, p) & 0xFFFF0000u;
        psum += __builtin_bit_cast(float, pu[r]);
      }
      uint2 pk;
      pk.x = (pu[0] >> 16) | pu[1];
      pk.y = (pu[2] >> 16) | pu[3];
      // row = own query (l16), cols jt*16 + quad*4 + r  (contiguous r)
      *(uint2*)(sPw + l16 * LU + jt * 16 + quad * 4) = pk;
    }
    psum += __shfl_xor(psum, 16);
    psum += __shfl_xor(psum, 32);
    lrun = lrun * alpha + psum;

    #pragma unroll
    for (int d4 = 0; d4 < 4; d4++)
      #pragma unroll
      for (int r = 0; r < 4; r++) oacc[d4][r] *= alpha;

    // wave-local drain: P writes complete before B-layout re-read
    asm volatile("s_waitcnt lgkmcnt(0)" ::: "memory");
    bf16x8 pf0 = ldfrag(sPw + l16 * LU + quad * 8);        // keys 0..31
    bf16x8 pf1 = ldfrag(sPw + l16 * LU + 32 + quad * 8);   // keys 32..63

    if (pre) {  // LDS-write the prefetched tile (other buffer, no reader yet)
      *(uint4*)(sKn + sr_ * 72 + sc_)      = pk0;
      *(uint4*)(sKn + sr_ * 72 + sc_ + 32) = pk1;
      *(uint4*)(sVn + sr_ * 72 + sc_)      = pv0;
      *(uint4*)(sVn + sr_ * 72 + sc_ + 32) = pv1;
    }

    // O^T = V^T . P^T : lane = query, rows = dcol
    #pragma unroll
    for (int d4 = 0; d4 < 4; d4++) {
      bf16x8 v0 = ldfrag(sVb + (d4 * 16 + l16) * 72 + quad * 8);
      bf16x8 v1 = ldfrag(sVb + (d4 * 16 + l16) * 72 + 32 + quad * 8);
      oacc[d4] = __builtin_amdgcn_mfma_f32_16x16x32_bf16(v0, pf0, oacc[d4], 0, 0, 0);
      oacc[d4] = __builtin_amdgcn_mfma_f32_16x16x32_bf16(v1, pf1, oacc[d4], 0, 0, 0);
    }
    __syncthreads();  // buf consumed by all waves; next buf visible
  }

  // epilogue: lane = query; rows = dcol = d4*16 + quad*4 + r
  const int query = m0 + w * 16 + l16;
  const float inv = 1.f / fmaxf(lrun, 1e-20f);
  u16* obase = Ob + ((size_t)query * 2 + b) * 768 + h * 64;
  #pragma unroll
  for (int d4 = 0; d4 < 4; d4++) {
    u16 t[4];
    #pragma unroll
    for (int r = 0; r < 4; r++) t[r] = f2bf(oacc[d4][r] * inv);
    *(uint2*)(obase + d4 * 16 + quad * 4) = *(const uint2*)t;
  }
}

extern "C" void kernel_launch(void* const* d_in, const int* in_sizes, int n_in,
                              void* d_out, int out_size, void* d_ws, size_t ws_size,
                              hipStream_t stream) {
  const float* x      = (const float*)d_in[0];
  const float* qkv_w  = (const float*)d_in[1];
  const float* qkv_b  = (const float*)d_in[2];
  const float* proj_w = (const float*)d_in[3];
  const float* proj_b = (const float*)d_in[4];
  float* out = (float*)d_out;

  char* ws = (char*)d_ws;
  // region 0 (6.29 MB): xb, then vtb (xb dead after QKV gemm)
  u16* xb  = (u16*)ws;
  u16* vtb = (u16*)ws;
  size_t off = (size_t)XSZ * 2;
  u16* qwb = (u16*)(ws + off); off += (size_t)QWSZ * 2;
  u16* pwb = (u16*)(ws + off); off += (size_t)PWSZ * 2;
  u16* qb  = (u16*)(ws + off); off += (size_t)XSZ * 2;
  u16* kb  = (u16*)(ws + off);            // st overlays kb (kb dead after flash1)
  u16* st  = kb;               off += (size_t)XSZ * 2;
  u16* vb  = (u16*)(ws + off);            // o1/o2 overlay vb (vb dead after transpose)
  u16* o1  = vb; u16* o2 = vb;
  // total ws use ~29.9 MB

  convert_all<<<2688, 256, 0, stream>>>(x, qkv_w, proj_w, xb, qwb, pwb);
  gemm_nt<0><<<dim3(18, 32), 256, 0, stream>>>(xb, qwb, qkv_b, qb, kb, vb, nullptr);
  transpose_v<<<dim3(32, 24), 256, 0, stream>>>(vb, vtb);
  flash_attn<1><<<dim3(32, 24), 256, 0, stream>>>(qb, kb, vtb, o1);
  gemm_nt<1><<<dim3(6, 64), 256, 0, stream>>>(o1, pwb, proj_b, st, nullptr, nullptr, nullptr);
  flash_attn<2><<<dim3(32, 24), 256, 0, stream>>>(st, st, vtb, o2);
  gemm_nt<2><<<dim3(6, 64), 256, 0, stream>>>(o2, pwb, proj_b, nullptr, nullptr, nullptr, out);
}

// Round 5
// 236.795 us; speedup vs baseline: 1.6114x; 1.0892x over previous
//
#include <hip/hip_runtime.h>

typedef unsigned short u16;
typedef __bf16 bf16_t;
typedef bf16_t bf16x8 __attribute__((ext_vector_type(8)));
typedef float f32x4 __attribute__((ext_vector_type(4)));

static __device__ __forceinline__ u16 f2bf(float f) {
  unsigned u = __builtin_bit_cast(unsigned, f);
  u += 0x7FFFu + ((u >> 16) & 1u);
  return (u16)(u >> 16);
}
static __device__ __forceinline__ bf16x8 ldfrag(const u16* p) {
  return __builtin_bit_cast(bf16x8, *(const uint4*)p);
}
static __device__ __forceinline__ float fexp2(float x) {
#if __has_builtin(__builtin_amdgcn_exp2f)
  return __builtin_amdgcn_exp2f(x);
#else
  return __expf(x * 0.69314718056f);
#endif
}
// pack [hi.b3 hi.b2 lo.b3 lo.b2] (two bf16 from two fp32 high-halves)
static __device__ __forceinline__ unsigned pack_hi16(unsigned hi, unsigned lo) {
#if __has_builtin(__builtin_amdgcn_perm)
  return __builtin_amdgcn_perm(hi, lo, 0x07060302u);
#else
  return (lo >> 16) | (hi & 0xFFFF0000u);
#endif
}
// XOR-swizzled tile: logical (row, 8-elem chunk) -> u16 offset, stride 64.
// Frag-read start bank = 4*(chunk ^ (row&7)) -> conflict-free 8-lane phases.
static __device__ __forceinline__ int sw(int row, int chunk) {
  return (row << 6) + ((chunk ^ (row & 7)) << 3);
}

#define QWSZ 1769472  // 2304*768
#define PWSZ 589824   // 768*768

// fp32 -> bf16 one-shot conversion of the two weight matrices.
__global__ __launch_bounds__(256) void convert_w(
    const float* __restrict__ qw, const float* __restrict__ pw,
    u16* __restrict__ qwb, u16* __restrict__ pwb)
{
  const int i = (blockIdx.x * 256 + threadIdx.x) * 8;
  const float* src; u16* dst; int off;
  if (i < QWSZ) { src = qw; dst = qwb; off = i; }
  else { src = pw; dst = pwb; off = i - QWSZ; }
  float4 a = *(const float4*)(src + off), b = *(const float4*)(src + off + 4);
  u16 t[8] = {f2bf(a.x), f2bf(a.y), f2bf(a.z), f2bf(a.w),
              f2bf(b.x), f2bf(b.y), f2bf(b.z), f2bf(b.w)};
  *(uint4*)(dst + off) = *(const uint4*)t;
}

// ---------------------------------------------------------------------------
// NT GEMM: C[m,n] = sum_k A[m,k] W[n,k] + bias[n]. K=768, swizzled LDS.
// MODE 0: BM=128, A = x fp32 [B,N,C] (converted during staging);
//         scatter q/k/v -> [BH,N,D] bf16
// MODE 1: BM=64,  A=o1 bf16 [N,B,C]; fused L2-normalize -> st bf16 [BH,N,D]
// MODE 2: BM=64,  A=o2 bf16 [N,B,C]; -> fp32 d_out [B,N,C]
// ---------------------------------------------------------------------------
template<int MODE>
__global__ __launch_bounds__(256, 2) void gemm_nt(
    const void* __restrict__ Araw, const u16* __restrict__ W,
    const float* __restrict__ bias,
    u16* __restrict__ d0, float* __restrict__ df)
{
  constexpr int BM = (MODE == 0) ? 128 : 64;
  constexpr int MI = (MODE == 0) ? 4 : 2;
  __shared__ __align__(16) u16 sA[BM * 64];
  __shared__ __align__(16) u16 sB[128 * 64];
  const float* Af = (const float*)Araw;
  const u16*   Ab = (const u16*)Araw;
  const int tid = threadIdx.x;
  const int m0 = blockIdx.y * BM, n0 = blockIdx.x * 128;
  const int w = tid >> 6, lane = tid & 63, l16 = lane & 15, quad = lane >> 4;
  const int wm = (w >> 1) * (BM / 2), wn = (w & 1) * 64;

  f32x4 acc[MI][4] = {};
  const int sr = tid >> 3, sc = (tid & 7) * 8, ch = tid & 7;

  for (int k0 = 0; k0 < 768; k0 += 64) {
    #pragma unroll
    for (int rr = 0; rr < BM; rr += 32) {
      if (MODE == 0) {
        const float* ap = Af + (size_t)(m0 + sr + rr) * 768 + k0 + sc;
        float4 a = *(const float4*)ap, b = *(const float4*)(ap + 4);
        u16 t[8] = {f2bf(a.x), f2bf(a.y), f2bf(a.z), f2bf(a.w),
                    f2bf(b.x), f2bf(b.y), f2bf(b.z), f2bf(b.w)};
        *(uint4*)(sA + sw(sr + rr, ch)) = *(const uint4*)t;
      } else {
        *(uint4*)(sA + sw(sr + rr, ch)) =
            *(const uint4*)(Ab + (size_t)(m0 + sr + rr) * 768 + k0 + sc);
      }
    }
    #pragma unroll
    for (int rr = 0; rr < 128; rr += 32)
      *(uint4*)(sB + sw(sr + rr, ch)) =
          *(const uint4*)(W + (size_t)(n0 + sr + rr) * 768 + k0 + sc);
    __syncthreads();
    #pragma unroll
    for (int ks = 0; ks < 2; ks++) {
      bf16x8 af[MI], bfv[4];
      #pragma unroll
      for (int i = 0; i < MI; i++)
        af[i] = ldfrag(sA + sw(wm + i * 16 + l16, ks * 4 + quad));
      #pragma unroll
      for (int i = 0; i < 4; i++)
        bfv[i] = ldfrag(sB + sw(wn + i * 16 + l16, ks * 4 + quad));
      #pragma unroll
      for (int mi = 0; mi < MI; mi++)
        #pragma unroll
        for (int ni = 0; ni < 4; ni++)
          acc[mi][ni] = __builtin_amdgcn_mfma_f32_16x16x32_bf16(af[mi], bfv[ni], acc[mi][ni], 0, 0, 0);
    }
    __syncthreads();
  }

  if (MODE == 0) {
    #pragma unroll
    for (int ni = 0; ni < 4; ni++) {
      const int gn = n0 + wn + ni * 16 + l16;
      const float bv = bias[gn];
      #pragma unroll
      for (int mi = 0; mi < MI; mi++) {
        #pragma unroll
        for (int r = 0; r < 4; r++) {
          const int gm = m0 + wm + mi * 16 + quad * 4 + r;
          const float v = acc[mi][ni][r] + bv;
          const int which = gn / 768, c = gn - which * 768, h = c >> 6, d = c & 63;
          const int b = gm >> 11, nt = gm & 2047;
          // d0 = qb base; q/k/v buffers are consecutive SZ-element regions
          u16* dst = d0 + (size_t)which * 3145728;
          dst[(((size_t)(b * 12 + h)) * 2048 + nt) * 64 + d] = f2bf(v);
        }
      }
    }
  } else if (MODE == 1) {
    // fused F.normalize: wave's 64-col span = one head (n0+wn is 64-aligned)
    #pragma unroll
    for (int mi = 0; mi < MI; mi++) {
      #pragma unroll
      for (int r = 0; r < 4; r++) {
        float v[4]; float ss = 0.f;
        #pragma unroll
        for (int ni = 0; ni < 4; ni++) {
          v[ni] = acc[mi][ni][r] + bias[n0 + wn + ni * 16 + l16];
          ss += v[ni] * v[ni];
        }
        #pragma unroll
        for (int off = 1; off < 16; off <<= 1) ss += __shfl_xor(ss, off);
        const float scl = 1.f / fmaxf(sqrtf(ss), 1e-12f);
        const int gm = m0 + wm + mi * 16 + quad * 4 + r;
        const int nt = gm >> 1, b = gm & 1;
        #pragma unroll
        for (int ni = 0; ni < 4; ni++) {
          const int gn = n0 + wn + ni * 16 + l16, h = gn >> 6, d = gn & 63;
          d0[(((size_t)(b * 12 + h)) * 2048 + nt) * 64 + d] = f2bf(v[ni] * scl);
        }
      }
    }
  } else {
    #pragma unroll
    for (int ni = 0; ni < 4; ni++) {
      const int gn = n0 + wn + ni * 16 + l16;
      const float bv = bias[gn];
      #pragma unroll
      for (int mi = 0; mi < MI; mi++) {
        #pragma unroll
        for (int r = 0; r < 4; r++) {
          const int gm = m0 + wm + mi * 16 + quad * 4 + r;
          const int nt = gm >> 1, b = gm & 1;
          df[((size_t)b * 2048 + nt) * 768 + gn] = acc[mi][ni][r] + bv;
        }
      }
    }
  }
}

// V [BH][N][64] bf16 -> VT [BH][64][N] bf16, 64x64 tiles through LDS.
__global__ __launch_bounds__(256) void transpose_v(const u16* __restrict__ in,
                                                   u16* __restrict__ out)
{
  constexpr int N = 2048;
  __shared__ __align__(16) u16 t[64 * 72];
  const int bh = blockIdx.y, n0 = blockIdx.x * 64;
  const int r = threadIdx.x >> 2, c0 = (threadIdx.x & 3) * 8;
  const u16* ip = in + ((size_t)bh * N + n0 + r) * 64;
  *(uint4*)(t + r * 72 + c0)      = *(const uint4*)(ip + c0);
  *(uint4*)(t + r * 72 + c0 + 32) = *(const uint4*)(ip + c0 + 32);
  __syncthreads();
  #pragma unroll
  for (int half = 0; half < 2; half++) {
    const int cc = c0 + half * 32;
    __align__(16) u16 tmp[8];
    #pragma unroll
    for (int i = 0; i < 8; i++) tmp[i] = t[(cc + i) * 72 + r];
    *(uint4*)(out + ((size_t)bh * 64 + r) * N + n0 + cc) = *(const uint4*)tmp;
  }
}

// ---------------------------------------------------------------------------
// Flash attention, S^T form (lane = query), static-M softmax (exact: softmax
// is invariant to the shift; bounds are range-safe), l via ones-MFMA.
// MODE 1: s*0.125, M=24 (|s|<=3.5 by norm bounds).
// MODE 2: s*10, s<0 masked; sim<=1 => s<=14.43, M=14.6, diag => l>=0.89.
// ---------------------------------------------------------------------------
template<int MODE>
__global__ __launch_bounds__(256, 3) void flash_attn(
    const u16* __restrict__ Qm, const u16* __restrict__ Km,
    const u16* __restrict__ VT, u16* __restrict__ Ob)
{
  constexpr int N = 2048;
  __shared__ __align__(16) u16 sU[64 * 64];   // Q staging, then per-wave P
  __shared__ __align__(16) u16 sK[2][64 * 64];
  __shared__ __align__(16) u16 sVT[2][64 * 64];
  const int tid = threadIdx.x;
  const int bh = blockIdx.y, m0 = blockIdx.x * 64;
  const int b = bh / 12, h = bh % 12;
  const int w = tid >> 6, lane = tid & 63, l16 = lane & 15, quad = lane >> 4;

  constexpr float SC = (MODE == 1) ? 0.18033688011112042f   // 0.125*log2(e)
                                   : 14.426950408889634f;   // 10*log2(e)
  constexpr float M0 = (MODE == 1) ? 24.f : 14.6f;

  const int sr_ = tid >> 2, c0 = tid & 3;  // staging: row, chunk pair (c0,c0+4)
  const u16* kbase = Km + (size_t)bh * N * 64;
  const u16* vbase = VT + (size_t)bh * 64 * N;
  {
    const u16* qp = Qm + ((size_t)bh * N + m0 + sr_) * 64;
    *(uint4*)(sU + sw(sr_, c0))     = *(const uint4*)(qp + c0 * 8);
    *(uint4*)(sU + sw(sr_, c0 + 4)) = *(const uint4*)(qp + c0 * 8 + 32);
    const u16* kp = kbase + (size_t)sr_ * 64;
    *(uint4*)(sK[0] + sw(sr_, c0))     = *(const uint4*)(kp + c0 * 8);
    *(uint4*)(sK[0] + sw(sr_, c0 + 4)) = *(const uint4*)(kp + c0 * 8 + 32);
    const u16* vp = vbase + (size_t)sr_ * N;
    *(uint4*)(sVT[0] + sw(sr_, c0))     = *(const uint4*)(vp + c0 * 8);
    *(uint4*)(sVT[0] + sw(sr_, c0 + 4)) = *(const uint4*)(vp + c0 * 8 + 32);
  }
  __syncthreads();
  // each wave reads only its own 16 rows (later overlaid with its P tile)
  bf16x8 qf0 = ldfrag(sU + sw(w * 16 + l16, quad));
  bf16x8 qf1 = ldfrag(sU + sw(w * 16 + l16, quad + 4));
  asm volatile("s_waitcnt lgkmcnt(0)" ::: "memory");

  bf16x8 ones;
  #pragma unroll
  for (int i = 0; i < 8; i++) ones[i] = (bf16_t)1.0f;

  f32x4 oacc[4] = {};
  f32x4 lacc = {};

  for (int it = 0; it < 32; it++) {
    const int buf = it & 1;
    const u16* sKb = sK[buf];
    const u16* sVb = sVT[buf];
    u16* sKn = sK[buf ^ 1];
    u16* sVn = sVT[buf ^ 1];

    // issue next tile's global loads now; LDS-write them later
    uint4 pk0, pk1, pv0, pv1;
    const bool pre = (it + 1 < 32);
    if (pre) {
      const int j1 = (it + 1) * 64;
      const u16* kp = kbase + (size_t)(j1 + sr_) * 64;
      pk0 = *(const uint4*)(kp + c0 * 8);
      pk1 = *(const uint4*)(kp + c0 * 8 + 32);
      const u16* vp = vbase + (size_t)sr_ * N + j1;
      pv0 = *(const uint4*)(vp + c0 * 8);
      pv1 = *(const uint4*)(vp + c0 * 8 + 32);
    }

    // S^T tiles: D[m=key][n=query] = K . Q^T
    f32x4 s[4];
    #pragma unroll
    for (int jt = 0; jt < 4; jt++) {
      f32x4 a = {};
      bf16x8 kf0 = ldfrag(sKb + sw(jt * 16 + l16, quad));
      bf16x8 kf1 = ldfrag(sKb + sw(jt * 16 + l16, quad + 4));
      a = __builtin_amdgcn_mfma_f32_16x16x32_bf16(kf0, qf0, a, 0, 0, 0);
      a = __builtin_amdgcn_mfma_f32_16x16x32_bf16(kf1, qf1, a, 0, 0, 0);
      s[jt] = a;
    }

    // p = exp2(s*SC - M0), masked->0; bf16-truncate; write to own P rows
    u16* sPw = sU;  // per-wave region: rows w*16 + l16
    #pragma unroll
    for (int jt = 0; jt < 4; jt++) {
      unsigned pu[4];
      #pragma unroll
      for (int r = 0; r < 4; r++) {
        const float a = s[jt][r];
        float p = fexp2(fmaf(a, SC, -M0));
        if (MODE == 2 && a < 0.f) p = 0.f;
        pu[r] = __builtin_bit_cast(unsigned, p) & 0xFFFF0000u;
      }
      uint2 pk;
      pk.x = pack_hi16(pu[1], pu[0]);
      pk.y = pack_hi16(pu[3], pu[2]);
      *(uint2*)(sPw + sw(w * 16 + l16, 2 * jt + (quad >> 1)) + (quad & 1) * 4) = pk;
    }

    // wave-local drain: P writes complete before B-layout re-read
    asm volatile("s_waitcnt lgkmcnt(0)" ::: "memory");
    bf16x8 pf0 = ldfrag(sPw + sw(w * 16 + l16, quad));      // keys 0..31
    bf16x8 pf1 = ldfrag(sPw + sw(w * 16 + l16, quad + 4));  // keys 32..63

    if (pre) {  // LDS-write the prefetched tile (other buffer, no reader yet)
      *(uint4*)(sKn + sw(sr_, c0))     = pk0;
      *(uint4*)(sKn + sw(sr_, c0 + 4)) = pk1;
      *(uint4*)(sVn + sw(sr_, c0))     = pv0;
      *(uint4*)(sVn + sw(sr_, c0 + 4)) = pv1;
    }

    // O^T = V^T . P^T ; l = ones . P^T  (all-MFMA accumulation, no rescale)
    #pragma unroll
    for (int d4 = 0; d4 < 4; d4++) {
      bf16x8 v0 = ldfrag(sVb + sw(d4 * 16 + l16, quad));
      bf16x8 v1 = ldfrag(sVb + sw(d4 * 16 + l16, quad + 4));
      oacc[d4] = __builtin_amdgcn_mfma_f32_16x16x32_bf16(v0, pf0, oacc[d4], 0, 0, 0);
      oacc[d4] = __builtin_amdgcn_mfma_f32_16x16x32_bf16(v1, pf1, oacc[d4], 0, 0, 0);
    }
    lacc = __builtin_amdgcn_mfma_f32_16x16x32_bf16(ones, pf0, lacc, 0, 0, 0);
    lacc = __builtin_amdgcn_mfma_f32_16x16x32_bf16(ones, pf1, lacc, 0, 0, 0);
    __syncthreads();  // buf consumed by all waves; next buf visible
  }

  // epilogue: lane = query l16; rows = dcol = d4*16 + quad*4 + r
  const int query = m0 + w * 16 + l16;
  const float inv = 1.f / fmaxf(lacc[0], 1e-30f);
  u16* obase = Ob + ((size_t)query * 2 + b) * 768 + h * 64;
  #pragma unroll
  for (int d4 = 0; d4 < 4; d4++) {
    u16 t[4];
    #pragma unroll
    for (int r = 0; r < 4; r++) t[r] = f2bf(oacc[d4][r] * inv);
    *(uint2*)(obase + d4 * 16 + quad * 4) = *(const uint2*)t;
  }
}

extern "C" void kernel_launch(void* const* d_in, const int* in_sizes, int n_in,
                              void* d_out, int out_size, void* d_ws, size_t ws_size,
                              hipStream_t stream) {
  const float* x      = (const float*)d_in[0];
  const float* qkv_w  = (const float*)d_in[1];
  const float* qkv_b  = (const float*)d_in[2];
  const float* proj_w = (const float*)d_in[3];
  const float* proj_b = (const float*)d_in[4];
  float* out = (float*)d_out;

  const size_t SZ = (size_t)24 * 2048 * 64;  // elems per [BH,N,D] buffer
  char* ws = (char*)d_ws;
  u16* vtb = (u16*)ws;
  size_t off = SZ * 2;
  u16* qwb = (u16*)(ws + off); off += (size_t)QWSZ * 2;
  u16* pwb = (u16*)(ws + off); off += (size_t)PWSZ * 2;
  u16* qb  = (u16*)(ws + off); off += SZ * 2 * 3;  // qb,kb,vb consecutive
  u16* kb  = qb + SZ;                              // st overlays kb
  u16* vb  = qb + SZ * 2;
  u16* st  = kb;
  u16* o1  = (u16*)(ws + off);                     // o2 overlays o1
  u16* o2  = o1;

  convert_w<<<1152, 256, 0, stream>>>(qkv_w, proj_w, qwb, pwb);
  gemm_nt<0><<<dim3(18, 32), 256, 0, stream>>>(x, qwb, qkv_b, qb, nullptr);
  transpose_v<<<dim3(32, 24), 256, 0, stream>>>(vb, vtb);
  flash_attn<1><<<dim3(32, 24), 256, 0, stream>>>(qb, kb, vtb, o1);
  gemm_nt<1><<<dim3(6, 64), 256, 0, stream>>>(o1, pwb, proj_b, st, nullptr);
  flash_attn<2><<<dim3(32, 24), 256, 0, stream>>>(st, st, vtb, o2);
  gemm_nt<2><<<dim3(6, 64), 256, 0, stream>>>(o2, pwb, proj_b, nullptr, out);
}